// Round 12
// baseline (149.578 us; speedup 1.0000x reference)
//
#include <hip/hip_runtime.h>
#include <stdint.h>

#define B_ 4
#define C_ 64
#define H_ 96
#define W_ 96
#define HP_ 48
#define WP_ 48
#define N_ (H_*W_)      // 9216
#define M_ (HP_*WP_)    // 2304
#define KD_ 64
#define OD_ 64
#define BN_EPS 1e-5f
#define LOG2E 1.4426950408889634f
#define SHIFT2 28.853900817779268f   // 20 * LOG2E
#define QT_ 48                        // q-tile: 768 blocks
#define QI_ (QT_/16)                  // 3 q-frags per block
#define QB_ (N_/QT_)                  // 192 q-tiles per batch
#define KVB_ 128                      // m-tile 128
#define NT2_ (M_/KVB_)                // 18 m-tiles (even — 2x unroll relies on it)
#define KBUF_ 16384                   // K tile bytes: 128 rows x 64 k x 2
#define BUF_ 32768                    // K + V per buffer
#define EAOFF_ 65536                  // ea after 2 buffers
// total smem = 65536 + 9216 = 74752 -> 2 blocks/CU

typedef __bf16 bf16_t;
typedef bf16_t bf16x8 __attribute__((ext_vector_type(8)));
typedef bf16_t bf16x4 __attribute__((ext_vector_type(4)));
typedef float f32x4 __attribute__((ext_vector_type(4)));
typedef short short4v __attribute__((ext_vector_type(4)));
typedef short short8v __attribute__((ext_vector_type(8)));

static __device__ __forceinline__ unsigned short f2bf(float f) {
    unsigned int u = __builtin_bit_cast(unsigned int, f);
    u += 0x7fffu + ((u >> 16) & 1u);
    return (unsigned short)(u >> 16);
}

// async global->LDS DMA, 16B per lane. LDS dest linear per wave; GLOBAL
// source is per-lane (staged row permutation + chunk swizzle are free).
static __device__ __forceinline__ void gl_lds16(const unsigned short* g, unsigned short* l) {
#if __has_builtin(__builtin_amdgcn_global_load_lds)
    __builtin_amdgcn_global_load_lds(
        (const __attribute__((address_space(1))) unsigned int*)(const void*)g,
        (__attribute__((address_space(3))) unsigned int*)(void*)l, 16, 0, 0);
#endif
}

static __device__ __forceinline__ void setprio1() {
#if __has_builtin(__builtin_amdgcn_s_setprio)
    __builtin_amdgcn_s_setprio(1);
#endif
}
static __device__ __forceinline__ void setprio0() {
#if __has_builtin(__builtin_amdgcn_s_setprio)
    __builtin_amdgcn_s_setprio(0);
#endif
}
static __device__ __forceinline__ void schedbar0() {
#if __has_builtin(__builtin_amdgcn_sched_barrier)
    __builtin_amdgcn_sched_barrier(0);
#endif
}
static __device__ __forceinline__ void rawbar() {
#if __has_builtin(__builtin_amdgcn_s_barrier)
    __builtin_amdgcn_s_barrier();
#else
    __syncthreads();
#endif
}

// ---------------- Kernel 1: fused pool(x,c2) + key conv + edge attention ----------------
__global__ __launch_bounds__(256) void prep_kernel(
    const float* __restrict__ x, const float* __restrict__ c2,
    const float* __restrict__ wq, const float* __restrict__ bq,
    const float* __restrict__ w1, const float* __restrict__ bnw, const float* __restrict__ bnb,
    const float* __restrict__ bnm, const float* __restrict__ bnv,
    const float* __restrict__ w2, const float* __restrict__ b2,
    unsigned short* __restrict__ kb, unsigned short* __restrict__ vb, float* __restrict__ ea) {

    __shared__ float lw1[OD_*2*C_];
    __shared__ float lwq[KD_*C_];
    __shared__ float xs[C_*33];
    __shared__ float c2s[C_*33];
    __shared__ float red[8][32];

    int tid = threadIdx.x;
    int b = blockIdx.x / 72;
    int m0 = (blockIdx.x % 72) * 32;

    for (int i = tid; i < OD_*2*C_; i += 256) lw1[i] = w1[i];
    for (int i = tid; i < KD_*C_; i += 256) lwq[i] = wq[i];
    for (int j = tid; j < 2048; j += 256) {
        int c = j >> 5, p = j & 31;
        int m = m0 + p;
        int hp = m / WP_, wp = m % WP_;
        size_t base = ((size_t)(b*C_ + c)*H_ + 2*hp)*W_ + 2*wp;
        const float* px = x + base;
        float mx = fmaxf(fmaxf(px[0], px[1]), fmaxf(px[W_], px[W_+1]));
        xs[c*33 + p] = mx;
        vb[(size_t)(b*C_ + c)*M_ + m] = f2bf(mx);
        const float* pc = c2 + base;
        c2s[c*33 + p] = fmaxf(fmaxf(pc[0], pc[1]), fmaxf(pc[W_], pc[W_+1]));
    }
    __syncthreads();

    int ml = tid & 31, oz = tid >> 5;
    int m = m0 + ml;

    float h[8] = {0,0,0,0,0,0,0,0};
    for (int c = 0; c < C_; c += 4) {
        float x0 = xs[c*33+ml], x1 = xs[(c+1)*33+ml], x2 = xs[(c+2)*33+ml], x3 = xs[(c+3)*33+ml];
        #pragma unroll
        for (int oi = 0; oi < 8; oi++) {
            const float4 wv = *(const float4*)&lwq[(oz*8 + oi)*C_ + c];
            h[oi] = fmaf(wv.x, x0, fmaf(wv.y, x1, fmaf(wv.z, x2, fmaf(wv.w, x3, h[oi]))));
        }
    }
    unsigned short tmp[8];
    #pragma unroll
    for (int oi = 0; oi < 8; oi++) tmp[oi] = f2bf(h[oi] + bq[oz*8 + oi]);
    *(uint4*)&kb[((size_t)b*M_ + m)*KD_ + oz*8] = *(const uint4*)tmp;

    float g[8] = {0,0,0,0,0,0,0,0};
    for (int c = 0; c < 2*C_; c += 4) {
        const float* srcb = (c < C_) ? &c2s[c*33] : &xs[(c - C_)*33];
        float x0 = srcb[ml], x1 = srcb[33+ml], x2 = srcb[66+ml], x3 = srcb[99+ml];
        #pragma unroll
        for (int oi = 0; oi < 8; oi++) {
            const float4 wv = *(const float4*)&lw1[(oz*8 + oi)*(2*C_) + c];
            g[oi] = fmaf(wv.x, x0, fmaf(wv.y, x1, fmaf(wv.z, x2, fmaf(wv.w, x3, g[oi]))));
        }
    }
    float z = 0.f;
    #pragma unroll
    for (int oi = 0; oi < 8; oi++) {
        int o = oz*8 + oi;
        float sc = bnw[o] * rsqrtf(bnv[o] + BN_EPS);
        float t = (g[oi] - bnm[o]) * sc + bnb[o];
        z += w2[o] * fmaxf(t, 0.f);
    }
    red[oz][ml] = z;
    __syncthreads();
    if (oz == 0) {
        float s = b2[0];
        #pragma unroll
        for (int i = 0; i < 8; i++) s += red[i][ml];
        ea[(size_t)b*M_ + m] = LOG2E / (1.f + __builtin_amdgcn_exp2f(-s * LOG2E));
    }
}

// ---------------- Kernel 2: flash attention, 128-m tiles, K=32 PV, T15 pipeline ----------------
// R12: T15 cross-tile stage split. R11 proved attn time is invariant to
// sync/instruction count -> the wall is the per-tile serial chain
// QK->exp->PV inside each barrier interval. Now QK(t+1) runs at the TAIL of
// step t (frags for t+1 already read into NXT regs), so step t's chain is
// only exp(t)->PV(t); QK overlaps the frag-read latency and the trans-pipe
// exp no longer sits behind a same-step matrix op. st double-buffered in
// two named StSets (+48 VGPR, budget 256 at 2 blocks/CU).
// Safety: each wave's lgkmcnt(0) before QK(t+1) precedes the t+1 barrier,
// so buf[t&1] is fully read before STAGE(t+2) overwrites it.
__global__ __launch_bounds__(256, 2) void attn_kernel(
    const float* __restrict__ wq, const float* __restrict__ bq,
    const unsigned short* __restrict__ kb, const unsigned short* __restrict__ vb,
    const float* __restrict__ ea, const float* __restrict__ x,
    const float* __restrict__ gamma_p, float* __restrict__ out) {

    // [K 16384 | V 16384] x2 = 65536, ea 9216 -> 74752 B
    // prologue overlay: qlds 6144 @EAOFF_ (consumed before ea copy)
    // epilogue overlay: o_red 26112 + l_red 768 = 26880 B @0 (fits)
    __shared__ __align__(16) char smem[74752];

    int tid = threadIdx.x;
    int wave = tid >> 6, lane = tid & 63, quad = lane >> 4, l16 = lane & 15;
    int blk = blockIdx.x;
    int b = (blk & 7) >> 1;                       // batch pinned to XCD pair
    int n_base = ((blk & 1) * (QB_/2) + (blk >> 3)) * QT_;
    int xsw = l16 & 7;

    // ---- fused q-conv via compensated bf16 MFMA (R10, unchanged) ----
    unsigned short* qlds = (unsigned short*)(smem + EAOFF_); // [48 n][64 k] bf16 swz
    {
        const float* xb = x + (size_t)b*C_*N_ + n_base;
        bf16x8 wh0, wh1, wl0, wl1;
        {
            float w8[8];
            unsigned short hs[8], ls[8];
            const float* wp0 = wq + (size_t)(wave*16 + l16)*C_ + quad*8;
            *(float4*)&w8[0] = *(const float4*)wp0;
            *(float4*)&w8[4] = *(const float4*)(wp0 + 4);
            #pragma unroll
            for (int j = 0; j < 8; j++) {
                hs[j] = f2bf(w8[j]);
                float hf = __builtin_bit_cast(float, (unsigned int)hs[j] << 16);
                ls[j] = f2bf(w8[j] - hf);
            }
            wh0 = __builtin_bit_cast(bf16x8, *(const uint4*)hs);
            wl0 = __builtin_bit_cast(bf16x8, *(const uint4*)ls);
            const float* wp1 = wp0 + 32;
            *(float4*)&w8[0] = *(const float4*)wp1;
            *(float4*)&w8[4] = *(const float4*)(wp1 + 4);
            #pragma unroll
            for (int j = 0; j < 8; j++) {
                hs[j] = f2bf(w8[j]);
                float hf = __builtin_bit_cast(float, (unsigned int)hs[j] << 16);
                ls[j] = f2bf(w8[j] - hf);
            }
            wh1 = __builtin_bit_cast(bf16x8, *(const uint4*)hs);
            wl1 = __builtin_bit_cast(bf16x8, *(const uint4*)ls);
        }
        float4 bq4 = *(const float4*)(bq + wave*16 + quad*4);

        f32x4 qacc[3];
        #pragma unroll
        for (int t = 0; t < 3; t++) qacc[t] = (f32x4){0.f,0.f,0.f,0.f};

        #pragma unroll
        for (int t = 0; t < 3; t++) {
            #pragma unroll
            for (int h = 0; h < 2; h++) {
                float v8[8];
                #pragma unroll
                for (int j = 0; j < 8; j++)
                    v8[j] = xb[(size_t)(h*32 + quad*8 + j)*N_ + t*16 + l16];
                unsigned short hs[8], ls[8];
                #pragma unroll
                for (int j = 0; j < 8; j++) {
                    hs[j] = f2bf(v8[j]);
                    float hf = __builtin_bit_cast(float, (unsigned int)hs[j] << 16);
                    ls[j] = f2bf(v8[j] - hf);
                }
                bf16x8 xh = __builtin_bit_cast(bf16x8, *(const uint4*)hs);
                bf16x8 xl = __builtin_bit_cast(bf16x8, *(const uint4*)ls);
                bf16x8 wh = h ? wh1 : wh0;
                bf16x8 wl = h ? wl1 : wl0;
#if __has_builtin(__builtin_amdgcn_mfma_f32_16x16x32_bf16)
                qacc[t] = __builtin_amdgcn_mfma_f32_16x16x32_bf16(wh, xh, qacc[t], 0, 0, 0);
                qacc[t] = __builtin_amdgcn_mfma_f32_16x16x32_bf16(wl, xh, qacc[t], 0, 0, 0);
                qacc[t] = __builtin_amdgcn_mfma_f32_16x16x32_bf16(wh, xl, qacc[t], 0, 0, 0);
#endif
            }
        }
        #pragma unroll
        for (int t = 0; t < 3; t++) {
            unsigned short q4[4];
            q4[0] = f2bf(qacc[t][0] + bq4.x);
            q4[1] = f2bf(qacc[t][1] + bq4.y);
            q4[2] = f2bf(qacc[t][2] + bq4.z);
            q4[3] = f2bf(qacc[t][3] + bq4.w);
            int n_abs = t*16 + l16;
            int kc = wave*2 + (quad >> 1);
            *(uint2*)&qlds[n_abs*64 + ((kc ^ (n_abs & 7)) << 3) + (quad & 1)*4] =
                *(const uint2*)q4;
        }
    }
    asm volatile("s_waitcnt lgkmcnt(0)" ::: "memory"); // qlds writes done (own wave)
    __syncthreads();                                   // all waves' q written

    // Q B-frags: B[col=q=qi*16+l16][k=quad*8+j]
    bf16x8 qf[QI_][2];
    #pragma unroll
    for (int qi = 0; qi < QI_; qi++) {
        const unsigned short* qp = qlds + (qi*16 + l16)*64;
        qf[qi][0] = __builtin_bit_cast(bf16x8, *(const uint4*)(qp + ((quad     ^ xsw) << 3)));
        qf[qi][1] = __builtin_bit_cast(bf16x8, *(const uint4*)(qp + (((quad+4) ^ xsw) << 3)));
    }
    asm volatile("s_waitcnt lgkmcnt(0)" ::: "memory"); // qf reads landed (own wave)
    __syncthreads();          // all waves done reading qlds before ea copy

    f32x4 o2[QI_][4]; // O^T partial: [qi][ct]
    f32x4 lacc[QI_];  // denominator partials via ones-MFMA
    #pragma unroll
    for (int qi = 0; qi < QI_; qi++) {
        lacc[qi] = (f32x4){0.f,0.f,0.f,0.f};
        #pragma unroll
        for (int ct = 0; ct < 4; ct++) o2[qi][ct] = (f32x4){0.f,0.f,0.f,0.f};
    }
    const unsigned short ones_u[8] = {0x3F80,0x3F80,0x3F80,0x3F80,0x3F80,0x3F80,0x3F80,0x3F80};
    bf16x8 ones8 = __builtin_bit_cast(bf16x8, *(const uint4*)ones_u);

    const unsigned short* kbB = kb + (size_t)b*M_*KD_;
    const unsigned short* vbB = vb + (size_t)b*C_*M_;
    const float* eaB = ea + (size_t)b*M_;

    // ---- staging invariants ----
    // K: LDS row R = p*32 + r8 holds global m = mb + p*32 + mloc(r8);
    //    mloc = (ii>>2)*8 + half*4 + (ii&3) — the P-repack-free permutation.
    int r8  = tid >> 3;                       // 0..31
    int mloc = (((r8 & 15) >> 2) << 3) + ((r8 >> 4) << 2) + (r8 & 3);
    int kcs = ((tid & 7) ^ (r8 & 7)) << 3;    // K chunk swizzle (shorts)
    int c16 = tid >> 4;                       // 0..15 (V c-row within pass)
    int vcs = ((tid & 15) ^ (c16 & 7)) << 3;  // V chunk swizzle (shorts)

    auto STAGE = [&](int mb, char* buf) {
        unsigned short* kd = (unsigned short*)buf;
        unsigned short* vd = (unsigned short*)(buf + KBUF_);
        gl_lds16(kbB + (size_t)(mb +  0 + mloc)*KD_ + kcs, kd + 0*2048 + tid*8);
        gl_lds16(kbB + (size_t)(mb + 32 + mloc)*KD_ + kcs, kd + 1*2048 + tid*8);
        gl_lds16(kbB + (size_t)(mb + 64 + mloc)*KD_ + kcs, kd + 2*2048 + tid*8);
        gl_lds16(kbB + (size_t)(mb + 96 + mloc)*KD_ + kcs, kd + 3*2048 + tid*8);
        gl_lds16(vbB + (size_t)( 0 + c16)*M_ + mb + vcs, vd + 0*2048 + tid*8);
        gl_lds16(vbB + (size_t)(16 + c16)*M_ + mb + vcs, vd + 1*2048 + tid*8);
        gl_lds16(vbB + (size_t)(32 + c16)*M_ + mb + vcs, vd + 2*2048 + tid*8);
        gl_lds16(vbB + (size_t)(48 + c16)*M_ + mb + vcs, vd + 3*2048 + tid*8);
    };

    // ---- ea -> LDS; then stage tiles 0+1 ----
    {
        const f32x4* eaV = (const f32x4*)eaB;
        f32x4* eaL = (f32x4*)(smem + EAOFF_);
        for (int i = tid; i < M_/4; i += 256) eaL[i] = eaV[i];
    }
    asm volatile("s_waitcnt lgkmcnt(0)" ::: "memory"); // ea ds_writes done (own wave)
    __syncthreads();                                   // all waves' ea visible
    STAGE(0,    smem);
    STAGE(128,  smem + BUF_);
    asm volatile("s_waitcnt vmcnt(8)" ::: "memory");   // tile0's 8 DMA done (own wave)
    rawbar();                                          // => all waves' tile0 done
    asm volatile("" ::: "memory");

    const float* lds_ea = (const float*)(smem + EAOFF_);

    // read offsets (shorts)
    int kOffA0 = (wave*32 + l16)*64 + ((quad       ^ xsw) << 3);
    int kOffA1 = (wave*32 + l16)*64 + (((quad + 4) ^ xsw) << 3);
    int kOffB0 = kOffA0 + 16*64;
    int kOffB1 = kOffA1 + 16*64;
    int vch    = ((wave*4 + quad) ^ xsw) << 3;
    int eaIdx  = wave*32 + quad*8;

    // frag + st double-buffers: NAMED sets (constant/unroll-idx access only)
    struct FragSet {
        bf16x8 kfA0, kfA1, kfB0, kfB1;
        bf16x8 va0, va1, va2, va3;
        f32x4 eA, eB;
    };
    struct StSet { f32x4 sA[QI_]; f32x4 sB[QI_]; };
    FragSet fA, fB;
    StSet sX, sY;

    // read frag set for tile 0 into fA (from buf0), then QK(0) -> sX
    {
        unsigned short* kc = (unsigned short*)smem;
        unsigned short* vc = (unsigned short*)(smem + KBUF_);
        fA.eA  = *(const f32x4*)&lds_ea[0*KVB_ + eaIdx];
        fA.eB  = *(const f32x4*)&lds_ea[0*KVB_ + eaIdx + 4];
        fA.kfA0 = __builtin_bit_cast(bf16x8, *(const uint4*)(kc + kOffA0));
        fA.kfA1 = __builtin_bit_cast(bf16x8, *(const uint4*)(kc + kOffA1));
        fA.kfB0 = __builtin_bit_cast(bf16x8, *(const uint4*)(kc + kOffB0));
        fA.kfB1 = __builtin_bit_cast(bf16x8, *(const uint4*)(kc + kOffB1));
        fA.va0 = __builtin_bit_cast(bf16x8, *(const uint4*)(vc + (0*16 + l16)*KVB_ + vch));
        fA.va1 = __builtin_bit_cast(bf16x8, *(const uint4*)(vc + (1*16 + l16)*KVB_ + vch));
        fA.va2 = __builtin_bit_cast(bf16x8, *(const uint4*)(vc + (2*16 + l16)*KVB_ + vch));
        fA.va3 = __builtin_bit_cast(bf16x8, *(const uint4*)(vc + (3*16 + l16)*KVB_ + vch));
    }
    asm volatile("s_waitcnt lgkmcnt(0)" ::: "memory");
    schedbar0();
    #pragma unroll
    for (int qi = 0; qi < QI_; qi++) {
        f32x4 zA = (f32x4){0.f,0.f,0.f,0.f};
        zA = __builtin_amdgcn_mfma_f32_16x16x32_bf16(fA.kfA0, qf[qi][0], zA, 0, 0, 0);
        zA = __builtin_amdgcn_mfma_f32_16x16x32_bf16(fA.kfA1, qf[qi][1], zA, 0, 0, 0);
        sX.sA[qi] = zA;
        f32x4 zB = (f32x4){0.f,0.f,0.f,0.f};
        zB = __builtin_amdgcn_mfma_f32_16x16x32_bf16(fA.kfB0, qf[qi][0], zB, 0, 0, 0);
        zB = __builtin_amdgcn_mfma_f32_16x16x32_bf16(fA.kfB1, qf[qi][1], zB, 0, 0, 0);
        sX.sB[qi] = zB;
    }

// one pipeline step: exp+PV of tile T_ (from SCUR/CUR), prefetch T_+1 frags
// into NXT, then QK(T_+1) -> SNXT at the tail (overlaps next step's waits).
#define ATTN_STEP(T_, CUR, NXT, SCUR, SNXT)                                            \
    {                                                                                  \
        const int t_ = (T_);                                                           \
        if (t_ < NT2_ - 1) {                                                           \
            asm volatile("s_waitcnt vmcnt(0)" ::: "memory");  /* tile t_+1 DMA done */ \
            schedbar0();                                                               \
            rawbar();                   /* acquire buf[(t_+1)&1], release buf[t_&1] */ \
            asm volatile("" ::: "memory");                                             \
            schedbar0();                                                               \
            if (t_ + 2 < NT2_) { STAGE((t_ + 2)*KVB_, smem + (t_ & 1)*BUF_); }         \
            unsigned short* kc_ = (unsigned short*)(smem + ((t_ + 1) & 1)*BUF_);       \
            unsigned short* vc_ = (unsigned short*)(smem + ((t_ + 1) & 1)*BUF_ + KBUF_); \
            NXT.eA  = *(const f32x4*)&lds_ea[(t_ + 1)*KVB_ + eaIdx];                   \
            NXT.eB  = *(const f32x4*)&lds_ea[(t_ + 1)*KVB_ + eaIdx + 4];               \
            NXT.kfA0 = __builtin_bit_cast(bf16x8, *(const uint4*)(kc_ + kOffA0));      \
            NXT.kfA1 = __builtin_bit_cast(bf16x8, *(const uint4*)(kc_ + kOffA1));      \
            NXT.kfB0 = __builtin_bit_cast(bf16x8, *(const uint4*)(kc_ + kOffB0));      \
            NXT.kfB1 = __builtin_bit_cast(bf16x8, *(const uint4*)(kc_ + kOffB1));      \
            NXT.va0 = __builtin_bit_cast(bf16x8, *(const uint4*)(vc_ + (0*16 + l16)*KVB_ + vch)); \
            NXT.va1 = __builtin_bit_cast(bf16x8, *(const uint4*)(vc_ + (1*16 + l16)*KVB_ + vch)); \
            NXT.va2 = __builtin_bit_cast(bf16x8, *(const uint4*)(vc_ + (2*16 + l16)*KVB_ + vch)); \
            NXT.va3 = __builtin_bit_cast(bf16x8, *(const uint4*)(vc_ + (3*16 + l16)*KVB_ + vch)); \
            schedbar0();                                                               \
        }                                                                              \
        /* ---- exp(t_) + PV(t_): the only serial chain this step ---- */              \
        bf16x8 pk[QI_];                                                                \
        _Pragma("unroll")                                                              \
        for (int qi = 0; qi < QI_; qi++) {                                             \
            f32x4 pA, pB;                                                              \
            pA[0] = __builtin_amdgcn_exp2f(fmaf(SCUR.sA[qi][0], CUR.eA[0], -SHIFT2));  \
            pA[1] = __builtin_amdgcn_exp2f(fmaf(SCUR.sA[qi][1], CUR.eA[1], -SHIFT2));  \
            pA[2] = __builtin_amdgcn_exp2f(fmaf(SCUR.sA[qi][2], CUR.eA[2], -SHIFT2));  \
            pA[3] = __builtin_amdgcn_exp2f(fmaf(SCUR.sA[qi][3], CUR.eA[3], -SHIFT2));  \
            pB[0] = __builtin_amdgcn_exp2f(fmaf(SCUR.sB[qi][0], CUR.eB[0], -SHIFT2));  \
            pB[1] = __builtin_amdgcn_exp2f(fmaf(SCUR.sB[qi][1], CUR.eB[1], -SHIFT2));  \
            pB[2] = __builtin_amdgcn_exp2f(fmaf(SCUR.sB[qi][2], CUR.eB[2], -SHIFT2));  \
            pB[3] = __builtin_amdgcn_exp2f(fmaf(SCUR.sB[qi][3], CUR.eB[3], -SHIFT2));  \
            short4v pa = __builtin_bit_cast(short4v, __builtin_convertvector(pA, bf16x4)); \
            short4v pb = __builtin_bit_cast(short4v, __builtin_convertvector(pB, bf16x4)); \
            short8v p8 = __builtin_shufflevector(pa, pb, 0, 1, 2, 3, 4, 5, 6, 7);      \
            pk[qi] = __builtin_bit_cast(bf16x8, p8);                                   \
        }                                                                              \
        setprio1();                                                                    \
        _Pragma("unroll")                                                              \
        for (int qi = 0; qi < QI_; qi++) {                                             \
            o2[qi][0] = __builtin_amdgcn_mfma_f32_16x16x32_bf16(CUR.va0, pk[qi], o2[qi][0], 0, 0, 0); \
            o2[qi][1] = __builtin_amdgcn_mfma_f32_16x16x32_bf16(CUR.va1, pk[qi], o2[qi][1], 0, 0, 0); \
            o2[qi][2] = __builtin_amdgcn_mfma_f32_16x16x32_bf16(CUR.va2, pk[qi], o2[qi][2], 0, 0, 0); \
            o2[qi][3] = __builtin_amdgcn_mfma_f32_16x16x32_bf16(CUR.va3, pk[qi], o2[qi][3], 0, 0, 0); \
            lacc[qi]  = __builtin_amdgcn_mfma_f32_16x16x32_bf16(ones8,   pk[qi], lacc[qi], 0, 0, 0); \
        }                                                                              \
        setprio0();                                                                    \
        /* ---- tail: QK(t_+1) from NXT (overlapped with frag-read latency) ---- */    \
        if (t_ < NT2_ - 1) {                                                           \
            asm volatile("s_waitcnt lgkmcnt(0)" ::: "memory"); /* NXT frags landed */  \
            schedbar0();                              /* rule #18: pin MFMAs below */  \
            setprio1();                                                                \
            _Pragma("unroll")                                                          \
            for (int qi = 0; qi < QI_; qi++) {                                         \
                f32x4 zA = (f32x4){0.f,0.f,0.f,0.f};                                   \
                zA = __builtin_amdgcn_mfma_f32_16x16x32_bf16(NXT.kfA0, qf[qi][0], zA, 0, 0, 0); \
                zA = __builtin_amdgcn_mfma_f32_16x16x32_bf16(NXT.kfA1, qf[qi][1], zA, 0, 0, 0); \
                SNXT.sA[qi] = zA;                                                      \
                f32x4 zB = (f32x4){0.f,0.f,0.f,0.f};                                   \
                zB = __builtin_amdgcn_mfma_f32_16x16x32_bf16(NXT.kfB0, qf[qi][0], zB, 0, 0, 0); \
                zB = __builtin_amdgcn_mfma_f32_16x16x32_bf16(NXT.kfB1, qf[qi][1], zB, 0, 0, 0); \
                SNXT.sB[qi] = zB;                                                      \
            }                                                                          \
            setprio0();                                                                \
        }                                                                              \
    }

    for (int t = 0; t < NT2_; t += 2) {
        ATTN_STEP(t,     fA, fB, sX, sY);
        ATTN_STEP(t + 1, fB, fA, sY, sX);
    }
#undef ATTN_STEP

    __syncthreads();   // all waves done with LDS K/V buffers before overlay

    // ---- epilogue: cross-wave reduction of O^T partials and denominators ----
    float* o_red0 = (float*)smem;            // [48 q][68 c]
    float* o_red1 = o_red0 + QT_*68;
    float* l_red  = o_red1 + QT_*68;         // [4][48]

    if (lane < 16) {
        #pragma unroll
        for (int qi = 0; qi < QI_; qi++) l_red[wave*QT_ + qi*16 + l16] = lacc[qi][0];
    }
    if (wave < 2) {
        float* od = (wave == 0) ? o_red0 : o_red1;
        #pragma unroll
        for (int qi = 0; qi < QI_; qi++)
            #pragma unroll
            for (int ct = 0; ct < 4; ct++)
                *(f32x4*)&od[(qi*16 + l16)*68 + ct*16 + quad*4] = o2[qi][ct];
    }
    __syncthreads();
    if (wave >= 2) {
        float* od = (wave == 2) ? o_red0 : o_red1;
        #pragma unroll
        for (int qi = 0; qi < QI_; qi++)
            #pragma unroll
            for (int ct = 0; ct < 4; ct++) {
                f32x4* p = (f32x4*)&od[(qi*16 + l16)*68 + ct*16 + quad*4];
                *p += o2[qi][ct];
            }
    }
    __syncthreads();
    if (tid < QT_) {
        float s = (l_red[tid] + l_red[QT_ + tid]) + (l_red[2*QT_ + tid] + l_red[3*QT_ + tid]);
        l_red[tid] = 1.f / s;
    }
    __syncthreads();

    float gmm = gamma_p[0];
    int c = tid >> 2, q4 = tid & 3;
    const float* xrow = x + ((size_t)b*C_ + c)*N_ + n_base;
    float* orow = out + ((size_t)b*C_ + c)*N_ + n_base;
    #pragma unroll
    for (int i = 0; i < QI_; i++) {
        int q0 = q4*4 + i*16;
        float4 xv = *(const float4*)(xrow + q0);
        float4 ov;
        float v0 = (o_red0[(q0+0)*68 + c] + o_red1[(q0+0)*68 + c]) * l_red[q0+0];
        float v1 = (o_red0[(q0+1)*68 + c] + o_red1[(q0+1)*68 + c]) * l_red[q0+1];
        float v2 = (o_red0[(q0+2)*68 + c] + o_red1[(q0+2)*68 + c]) * l_red[q0+2];
        float v3 = (o_red0[(q0+3)*68 + c] + o_red1[(q0+3)*68 + c]) * l_red[q0+3];
        ov.x = fmaf(gmm, v0, xv.x);
        ov.y = fmaf(gmm, v1, xv.y);
        ov.z = fmaf(gmm, v2, xv.z);
        ov.w = fmaf(gmm, v3, xv.w);
        *(float4*)(orow + q0) = ov;
    }
}

extern "C" void kernel_launch(void* const* d_in, const int* in_sizes, int n_in,
                              void* d_out, int out_size, void* d_ws, size_t ws_size,
                              hipStream_t stream) {
    const float* c2    = (const float*)d_in[0];
    const float* x     = (const float*)d_in[1];
    const float* w_ea1 = (const float*)d_in[2];
    const float* bn_w  = (const float*)d_in[3];
    const float* bn_b  = (const float*)d_in[4];
    const float* bn_m  = (const float*)d_in[5];
    const float* bn_v  = (const float*)d_in[6];
    const float* w_ea2 = (const float*)d_in[7];
    const float* b_ea2 = (const float*)d_in[8];
    const float* w_q   = (const float*)d_in[9];
    const float* b_q   = (const float*)d_in[10];
    const float* gamma = (const float*)d_in[11];
    float* out = (float*)d_out;

    char* ws = (char*)d_ws;
    float* ea            = (float*)(ws + 0);                // 36864 B
    unsigned short* kb   = (unsigned short*)(ws + 36864);   // 1179648 B
    unsigned short* vb   = (unsigned short*)(ws + 1216512); // 1179648 B

    prep_kernel<<<dim3((B_*M_)/32), dim3(256), 0, stream>>>(x, c2, w_q, b_q,
        w_ea1, bn_w, bn_b, bn_m, bn_v, w_ea2, b_ea2, kb, vb, ea);
    attn_kernel<<<dim3(B_*QB_), dim3(256), 0, stream>>>(w_q, b_q, kb, vb, ea, x, gamma, out);
}

// Round 13
// 146.050 us; speedup vs baseline: 1.0242x; 1.0242x over previous
//
#include <hip/hip_runtime.h>
#include <stdint.h>

#define B_ 4
#define C_ 64
#define H_ 96
#define W_ 96
#define HP_ 48
#define WP_ 48
#define N_ (H_*W_)      // 9216
#define M_ (HP_*WP_)    // 2304
#define KD_ 64
#define OD_ 64
#define BN_EPS 1e-5f
#define LOG2E 1.4426950408889634f
#define QT_ 48                        // q-tile: 768 blocks
#define QI_ (QT_/16)                  // 3 q-frags per block
#define QB_ (N_/QT_)                  // 192 q-tiles per batch
#define KVB_ 128                      // m-tile 128
#define NT2_ (M_/KVB_)                // 18 m-tiles (even — 2x unroll relies on it)
#define KBUF_ 16384                   // K tile bytes: 128 rows x 64 k x 2
#define BUF_ 32768                    // K + V per buffer
// total smem = 2*BUF_ = 65536 -> 2 blocks/CU

typedef __bf16 bf16_t;
typedef bf16_t bf16x8 __attribute__((ext_vector_type(8)));
typedef bf16_t bf16x4 __attribute__((ext_vector_type(4)));
typedef float f32x4 __attribute__((ext_vector_type(4)));
typedef short short4v __attribute__((ext_vector_type(4)));
typedef short short8v __attribute__((ext_vector_type(8)));

static __device__ __forceinline__ unsigned short f2bf(float f) {
    unsigned int u = __builtin_bit_cast(unsigned int, f);
    u += 0x7fffu + ((u >> 16) & 1u);
    return (unsigned short)(u >> 16);
}

// async global->LDS DMA, 16B per lane. LDS dest linear per wave; GLOBAL
// source is per-lane (staged row permutation + chunk swizzle are free).
static __device__ __forceinline__ void gl_lds16(const unsigned short* g, unsigned short* l) {
#if __has_builtin(__builtin_amdgcn_global_load_lds)
    __builtin_amdgcn_global_load_lds(
        (const __attribute__((address_space(1))) unsigned int*)(const void*)g,
        (__attribute__((address_space(3))) unsigned int*)(void*)l, 16, 0, 0);
#endif
}

static __device__ __forceinline__ void setprio1() {
#if __has_builtin(__builtin_amdgcn_s_setprio)
    __builtin_amdgcn_s_setprio(1);
#endif
}
static __device__ __forceinline__ void setprio0() {
#if __has_builtin(__builtin_amdgcn_s_setprio)
    __builtin_amdgcn_s_setprio(0);
#endif
}
static __device__ __forceinline__ void schedbar0() {
#if __has_builtin(__builtin_amdgcn_sched_barrier)
    __builtin_amdgcn_sched_barrier(0);
#endif
}
static __device__ __forceinline__ void rawbar() {
#if __has_builtin(__builtin_amdgcn_s_barrier)
    __builtin_amdgcn_s_barrier();
#else
    __syncthreads();
#endif
}

// ---------------- Kernel 1: fused pool(x,c2) + edge attention + SCALED key conv ----------
// R13: edge attention computed FIRST; k rows are scaled by ea[m]*LOG2E at
// write time (softmax(energy*ea) == softmax over q·(ea*k) — ea is constant
// per m-column). Rounding (k*ea) to bf16 carries the same 2^-8 relative
// error as rounding k alone. No ea global output — attn no longer needs it.
__global__ __launch_bounds__(256) void prep_kernel(
    const float* __restrict__ x, const float* __restrict__ c2,
    const float* __restrict__ wq, const float* __restrict__ bq,
    const float* __restrict__ w1, const float* __restrict__ bnw, const float* __restrict__ bnb,
    const float* __restrict__ bnm, const float* __restrict__ bnv,
    const float* __restrict__ w2, const float* __restrict__ b2,
    unsigned short* __restrict__ kb, unsigned short* __restrict__ vb) {

    __shared__ float lw1[OD_*2*C_];
    __shared__ float lwq[KD_*C_];
    __shared__ float xs[C_*33];
    __shared__ float c2s[C_*33];
    __shared__ float red[8][32];
    __shared__ float eaf[32];

    int tid = threadIdx.x;
    int b = blockIdx.x / 72;
    int m0 = (blockIdx.x % 72) * 32;

    for (int i = tid; i < OD_*2*C_; i += 256) lw1[i] = w1[i];
    for (int i = tid; i < KD_*C_; i += 256) lwq[i] = wq[i];
    for (int j = tid; j < 2048; j += 256) {
        int c = j >> 5, p = j & 31;
        int m = m0 + p;
        int hp = m / WP_, wp = m % WP_;
        size_t base = ((size_t)(b*C_ + c)*H_ + 2*hp)*W_ + 2*wp;
        const float* px = x + base;
        float mx = fmaxf(fmaxf(px[0], px[1]), fmaxf(px[W_], px[W_+1]));
        xs[c*33 + p] = mx;
        vb[(size_t)(b*C_ + c)*M_ + m] = f2bf(mx);
        const float* pc = c2 + base;
        c2s[c*33 + p] = fmaxf(fmaxf(pc[0], pc[1]), fmaxf(pc[W_], pc[W_+1]));
    }
    __syncthreads();

    int ml = tid & 31, oz = tid >> 5;
    int m = m0 + ml;

    // ---- edge attention first ----
    float g[8] = {0,0,0,0,0,0,0,0};
    for (int c = 0; c < 2*C_; c += 4) {
        const float* srcb = (c < C_) ? &c2s[c*33] : &xs[(c - C_)*33];
        float x0 = srcb[ml], x1 = srcb[33+ml], x2 = srcb[66+ml], x3 = srcb[99+ml];
        #pragma unroll
        for (int oi = 0; oi < 8; oi++) {
            const float4 wv = *(const float4*)&lw1[(oz*8 + oi)*(2*C_) + c];
            g[oi] = fmaf(wv.x, x0, fmaf(wv.y, x1, fmaf(wv.z, x2, fmaf(wv.w, x3, g[oi]))));
        }
    }
    float z = 0.f;
    #pragma unroll
    for (int oi = 0; oi < 8; oi++) {
        int o = oz*8 + oi;
        float sc = bnw[o] * rsqrtf(bnv[o] + BN_EPS);
        float t = (g[oi] - bnm[o]) * sc + bnb[o];
        z += w2[o] * fmaxf(t, 0.f);
    }
    red[oz][ml] = z;
    __syncthreads();
    if (oz == 0) {
        float s = b2[0];
        #pragma unroll
        for (int i = 0; i < 8; i++) s += red[i][ml];
        eaf[ml] = LOG2E / (1.f + __builtin_amdgcn_exp2f(-s * LOG2E));
    }
    __syncthreads();

    // ---- key conv, scaled by eaf[m] ----
    float h[8] = {0,0,0,0,0,0,0,0};
    for (int c = 0; c < C_; c += 4) {
        float x0 = xs[c*33+ml], x1 = xs[(c+1)*33+ml], x2 = xs[(c+2)*33+ml], x3 = xs[(c+3)*33+ml];
        #pragma unroll
        for (int oi = 0; oi < 8; oi++) {
            const float4 wv = *(const float4*)&lwq[(oz*8 + oi)*C_ + c];
            h[oi] = fmaf(wv.x, x0, fmaf(wv.y, x1, fmaf(wv.z, x2, fmaf(wv.w, x3, h[oi]))));
        }
    }
    float fac = eaf[ml];
    unsigned short tmp[8];
    #pragma unroll
    for (int oi = 0; oi < 8; oi++) tmp[oi] = f2bf((h[oi] + bq[oz*8 + oi]) * fac);
    *(uint4*)&kb[((size_t)b*M_ + m)*KD_ + oz*8] = *(const uint4*)tmp;
}

// ---------------- Kernel 2: flash attention, 128-m tiles, K=32 PV, T15, no-ea ----------------
// R13: ea folded into kb (prep) and the 2^-SHIFT2 constant cancels between
// softmax numerator and denominator -> P = exp2(st) DIRECTLY. The entire
// per-P-element VALU prefix (fmaf) and all ea plumbing (prologue copy,
// per-step ds_reads, e4 regs, 9216B LDS) are deleted. Everything else is
// the R12 structure (T15 QK-hoist, K=32 PV via staged row permutation).
__global__ __launch_bounds__(256, 2) void attn_kernel(
    const float* __restrict__ wq, const float* __restrict__ bq,
    const unsigned short* __restrict__ kb, const unsigned short* __restrict__ vb,
    const float* __restrict__ x, const float* __restrict__ gamma_p, float* __restrict__ out) {

    // [K 16384 | V 16384] x2 = 65536 B
    // prologue overlay: qlds 6144 @0 (consumed before STAGE(0) overwrites)
    // epilogue overlay: o_red 26112 + l_red 768 = 26880 B @0 (fits)
    __shared__ __align__(16) char smem[65536];

    int tid = threadIdx.x;
    int wave = tid >> 6, lane = tid & 63, quad = lane >> 4, l16 = lane & 15;
    int blk = blockIdx.x;
    int b = (blk & 7) >> 1;                       // batch pinned to XCD pair
    int n_base = ((blk & 1) * (QB_/2) + (blk >> 3)) * QT_;
    int xsw = l16 & 7;

    // ---- fused q-conv via compensated bf16 MFMA (R10, unchanged) ----
    unsigned short* qlds = (unsigned short*)smem; // [48 n][64 k] bf16 swz (buf0 overlay)
    {
        const float* xb = x + (size_t)b*C_*N_ + n_base;
        bf16x8 wh0, wh1, wl0, wl1;
        {
            float w8[8];
            unsigned short hs[8], ls[8];
            const float* wp0 = wq + (size_t)(wave*16 + l16)*C_ + quad*8;
            *(float4*)&w8[0] = *(const float4*)wp0;
            *(float4*)&w8[4] = *(const float4*)(wp0 + 4);
            #pragma unroll
            for (int j = 0; j < 8; j++) {
                hs[j] = f2bf(w8[j]);
                float hf = __builtin_bit_cast(float, (unsigned int)hs[j] << 16);
                ls[j] = f2bf(w8[j] - hf);
            }
            wh0 = __builtin_bit_cast(bf16x8, *(const uint4*)hs);
            wl0 = __builtin_bit_cast(bf16x8, *(const uint4*)ls);
            const float* wp1 = wp0 + 32;
            *(float4*)&w8[0] = *(const float4*)wp1;
            *(float4*)&w8[4] = *(const float4*)(wp1 + 4);
            #pragma unroll
            for (int j = 0; j < 8; j++) {
                hs[j] = f2bf(w8[j]);
                float hf = __builtin_bit_cast(float, (unsigned int)hs[j] << 16);
                ls[j] = f2bf(w8[j] - hf);
            }
            wh1 = __builtin_bit_cast(bf16x8, *(const uint4*)hs);
            wl1 = __builtin_bit_cast(bf16x8, *(const uint4*)ls);
        }
        float4 bq4 = *(const float4*)(bq + wave*16 + quad*4);

        f32x4 qacc[3];
        #pragma unroll
        for (int t = 0; t < 3; t++) qacc[t] = (f32x4){0.f,0.f,0.f,0.f};

        #pragma unroll
        for (int t = 0; t < 3; t++) {
            #pragma unroll
            for (int h = 0; h < 2; h++) {
                float v8[8];
                #pragma unroll
                for (int j = 0; j < 8; j++)
                    v8[j] = xb[(size_t)(h*32 + quad*8 + j)*N_ + t*16 + l16];
                unsigned short hs[8], ls[8];
                #pragma unroll
                for (int j = 0; j < 8; j++) {
                    hs[j] = f2bf(v8[j]);
                    float hf = __builtin_bit_cast(float, (unsigned int)hs[j] << 16);
                    ls[j] = f2bf(v8[j] - hf);
                }
                bf16x8 xh = __builtin_bit_cast(bf16x8, *(const uint4*)hs);
                bf16x8 xl = __builtin_bit_cast(bf16x8, *(const uint4*)ls);
                bf16x8 wh = h ? wh1 : wh0;
                bf16x8 wl = h ? wl1 : wl0;
#if __has_builtin(__builtin_amdgcn_mfma_f32_16x16x32_bf16)
                qacc[t] = __builtin_amdgcn_mfma_f32_16x16x32_bf16(wh, xh, qacc[t], 0, 0, 0);
                qacc[t] = __builtin_amdgcn_mfma_f32_16x16x32_bf16(wl, xh, qacc[t], 0, 0, 0);
                qacc[t] = __builtin_amdgcn_mfma_f32_16x16x32_bf16(wh, xl, qacc[t], 0, 0, 0);
#endif
            }
        }
        #pragma unroll
        for (int t = 0; t < 3; t++) {
            unsigned short q4[4];
            q4[0] = f2bf(qacc[t][0] + bq4.x);
            q4[1] = f2bf(qacc[t][1] + bq4.y);
            q4[2] = f2bf(qacc[t][2] + bq4.z);
            q4[3] = f2bf(qacc[t][3] + bq4.w);
            int n_abs = t*16 + l16;
            int kc = wave*2 + (quad >> 1);
            *(uint2*)&qlds[n_abs*64 + ((kc ^ (n_abs & 7)) << 3) + (quad & 1)*4] =
                *(const uint2*)q4;
        }
    }
    asm volatile("s_waitcnt lgkmcnt(0)" ::: "memory"); // qlds writes done (own wave)
    __syncthreads();                                   // all waves' q written

    // Q B-frags: B[col=q=qi*16+l16][k=quad*8+j]
    bf16x8 qf[QI_][2];
    #pragma unroll
    for (int qi = 0; qi < QI_; qi++) {
        const unsigned short* qp = qlds + (qi*16 + l16)*64;
        qf[qi][0] = __builtin_bit_cast(bf16x8, *(const uint4*)(qp + ((quad     ^ xsw) << 3)));
        qf[qi][1] = __builtin_bit_cast(bf16x8, *(const uint4*)(qp + (((quad+4) ^ xsw) << 3)));
    }
    asm volatile("s_waitcnt lgkmcnt(0)" ::: "memory"); // qf reads landed (own wave)
    __syncthreads();          // all waves done reading qlds before STAGE overwrites

    f32x4 o2[QI_][4]; // O^T partial: [qi][ct]
    f32x4 lacc[QI_];  // denominator partials via ones-MFMA
    #pragma unroll
    for (int qi = 0; qi < QI_; qi++) {
        lacc[qi] = (f32x4){0.f,0.f,0.f,0.f};
        #pragma unroll
        for (int ct = 0; ct < 4; ct++) o2[qi][ct] = (f32x4){0.f,0.f,0.f,0.f};
    }
    const unsigned short ones_u[8] = {0x3F80,0x3F80,0x3F80,0x3F80,0x3F80,0x3F80,0x3F80,0x3F80};
    bf16x8 ones8 = __builtin_bit_cast(bf16x8, *(const uint4*)ones_u);

    const unsigned short* kbB = kb + (size_t)b*M_*KD_;
    const unsigned short* vbB = vb + (size_t)b*C_*M_;

    // ---- staging invariants ----
    // K: LDS row R = p*32 + r8 holds global m = mb + p*32 + mloc(r8);
    //    mloc = (ii>>2)*8 + half*4 + (ii&3) — the P-repack-free permutation.
    int r8  = tid >> 3;                       // 0..31
    int mloc = (((r8 & 15) >> 2) << 3) + ((r8 >> 4) << 2) + (r8 & 3);
    int kcs = ((tid & 7) ^ (r8 & 7)) << 3;    // K chunk swizzle (shorts)
    int c16 = tid >> 4;                       // 0..15 (V c-row within pass)
    int vcs = ((tid & 15) ^ (c16 & 7)) << 3;  // V chunk swizzle (shorts)

    auto STAGE = [&](int mb, char* buf) {
        unsigned short* kd = (unsigned short*)buf;
        unsigned short* vd = (unsigned short*)(buf + KBUF_);
        gl_lds16(kbB + (size_t)(mb +  0 + mloc)*KD_ + kcs, kd + 0*2048 + tid*8);
        gl_lds16(kbB + (size_t)(mb + 32 + mloc)*KD_ + kcs, kd + 1*2048 + tid*8);
        gl_lds16(kbB + (size_t)(mb + 64 + mloc)*KD_ + kcs, kd + 2*2048 + tid*8);
        gl_lds16(kbB + (size_t)(mb + 96 + mloc)*KD_ + kcs, kd + 3*2048 + tid*8);
        gl_lds16(vbB + (size_t)( 0 + c16)*M_ + mb + vcs, vd + 0*2048 + tid*8);
        gl_lds16(vbB + (size_t)(16 + c16)*M_ + mb + vcs, vd + 1*2048 + tid*8);
        gl_lds16(vbB + (size_t)(32 + c16)*M_ + mb + vcs, vd + 2*2048 + tid*8);
        gl_lds16(vbB + (size_t)(48 + c16)*M_ + mb + vcs, vd + 3*2048 + tid*8);
    };

    STAGE(0,    smem);
    STAGE(128,  smem + BUF_);
    asm volatile("s_waitcnt vmcnt(8)" ::: "memory");   // tile0's 8 DMA done (own wave)
    rawbar();                                          // => all waves' tile0 done
    asm volatile("" ::: "memory");

    // read offsets (shorts)
    int kOffA0 = (wave*32 + l16)*64 + ((quad       ^ xsw) << 3);
    int kOffA1 = (wave*32 + l16)*64 + (((quad + 4) ^ xsw) << 3);
    int kOffB0 = kOffA0 + 16*64;
    int kOffB1 = kOffA1 + 16*64;
    int vch    = ((wave*4 + quad) ^ xsw) << 3;

    // frag + st double-buffers: NAMED sets (constant/unroll-idx access only)
    struct FragSet {
        bf16x8 kfA0, kfA1, kfB0, kfB1;
        bf16x8 va0, va1, va2, va3;
    };
    struct StSet { f32x4 sA[QI_]; f32x4 sB[QI_]; };
    FragSet fA, fB;
    StSet sX, sY;

    // read frag set for tile 0 into fA (from buf0), then QK(0) -> sX
    {
        unsigned short* kc = (unsigned short*)smem;
        unsigned short* vc = (unsigned short*)(smem + KBUF_);
        fA.kfA0 = __builtin_bit_cast(bf16x8, *(const uint4*)(kc + kOffA0));
        fA.kfA1 = __builtin_bit_cast(bf16x8, *(const uint4*)(kc + kOffA1));
        fA.kfB0 = __builtin_bit_cast(bf16x8, *(const uint4*)(kc + kOffB0));
        fA.kfB1 = __builtin_bit_cast(bf16x8, *(const uint4*)(kc + kOffB1));
        fA.va0 = __builtin_bit_cast(bf16x8, *(const uint4*)(vc + (0*16 + l16)*KVB_ + vch));
        fA.va1 = __builtin_bit_cast(bf16x8, *(const uint4*)(vc + (1*16 + l16)*KVB_ + vch));
        fA.va2 = __builtin_bit_cast(bf16x8, *(const uint4*)(vc + (2*16 + l16)*KVB_ + vch));
        fA.va3 = __builtin_bit_cast(bf16x8, *(const uint4*)(vc + (3*16 + l16)*KVB_ + vch));
    }
    asm volatile("s_waitcnt lgkmcnt(0)" ::: "memory");
    schedbar0();
    #pragma unroll
    for (int qi = 0; qi < QI_; qi++) {
        f32x4 zA = (f32x4){0.f,0.f,0.f,0.f};
        zA = __builtin_amdgcn_mfma_f32_16x16x32_bf16(fA.kfA0, qf[qi][0], zA, 0, 0, 0);
        zA = __builtin_amdgcn_mfma_f32_16x16x32_bf16(fA.kfA1, qf[qi][1], zA, 0, 0, 0);
        sX.sA[qi] = zA;
        f32x4 zB = (f32x4){0.f,0.f,0.f,0.f};
        zB = __builtin_amdgcn_mfma_f32_16x16x32_bf16(fA.kfB0, qf[qi][0], zB, 0, 0, 0);
        zB = __builtin_amdgcn_mfma_f32_16x16x32_bf16(fA.kfB1, qf[qi][1], zB, 0, 0, 0);
        sX.sB[qi] = zB;
    }

// one pipeline step: exp+PV of tile T_ (SCUR/CUR), prefetch T_+1 frags into
// NXT, then QK(T_+1) -> SNXT at the tail. P = exp2(st) directly (no shift).
#define ATTN_STEP(T_, CUR, NXT, SCUR, SNXT)                                            \
    {                                                                                  \
        const int t_ = (T_);                                                           \
        if (t_ < NT2_ - 1) {                                                           \
            asm volatile("s_waitcnt vmcnt(0)" ::: "memory");  /* tile t_+1 DMA done */ \
            schedbar0();                                                               \
            rawbar();                   /* acquire buf[(t_+1)&1], release buf[t_&1] */ \
            asm volatile("" ::: "memory");                                             \
            schedbar0();                                                               \
            if (t_ + 2 < NT2_) { STAGE((t_ + 2)*KVB_, smem + (t_ & 1)*BUF_); }         \
            unsigned short* kc_ = (unsigned short*)(smem + ((t_ + 1) & 1)*BUF_);       \
            unsigned short* vc_ = (unsigned short*)(smem + ((t_ + 1) & 1)*BUF_ + KBUF_); \
            NXT.kfA0 = __builtin_bit_cast(bf16x8, *(const uint4*)(kc_ + kOffA0));      \
            NXT.kfA1 = __builtin_bit_cast(bf16x8, *(const uint4*)(kc_ + kOffA1));      \
            NXT.kfB0 = __builtin_bit_cast(bf16x8, *(const uint4*)(kc_ + kOffB0));      \
            NXT.kfB1 = __builtin_bit_cast(bf16x8, *(const uint4*)(kc_ + kOffB1));      \
            NXT.va0 = __builtin_bit_cast(bf16x8, *(const uint4*)(vc_ + (0*16 + l16)*KVB_ + vch)); \
            NXT.va1 = __builtin_bit_cast(bf16x8, *(const uint4*)(vc_ + (1*16 + l16)*KVB_ + vch)); \
            NXT.va2 = __builtin_bit_cast(bf16x8, *(const uint4*)(vc_ + (2*16 + l16)*KVB_ + vch)); \
            NXT.va3 = __builtin_bit_cast(bf16x8, *(const uint4*)(vc_ + (3*16 + l16)*KVB_ + vch)); \
            schedbar0();                                                               \
        }                                                                              \
        /* ---- exp(t_) + PV(t_): the only serial chain this step ---- */              \
        bf16x8 pk[QI_];                                                                \
        _Pragma("unroll")                                                              \
        for (int qi = 0; qi < QI_; qi++) {                                             \
            f32x4 pA, pB;                                                              \
            pA[0] = __builtin_amdgcn_exp2f(SCUR.sA[qi][0]);                            \
            pA[1] = __builtin_amdgcn_exp2f(SCUR.sA[qi][1]);                            \
            pA[2] = __builtin_amdgcn_exp2f(SCUR.sA[qi][2]);                            \
            pA[3] = __builtin_amdgcn_exp2f(SCUR.sA[qi][3]);                            \
            pB[0] = __builtin_amdgcn_exp2f(SCUR.sB[qi][0]);                            \
            pB[1] = __builtin_amdgcn_exp2f(SCUR.sB[qi][1]);                            \
            pB[2] = __builtin_amdgcn_exp2f(SCUR.sB[qi][2]);                            \
            pB[3] = __builtin_amdgcn_exp2f(SCUR.sB[qi][3]);                            \
            short4v pa = __builtin_bit_cast(short4v, __builtin_convertvector(pA, bf16x4)); \
            short4v pb = __builtin_bit_cast(short4v, __builtin_convertvector(pB, bf16x4)); \
            short8v p8 = __builtin_shufflevector(pa, pb, 0, 1, 2, 3, 4, 5, 6, 7);      \
            pk[qi] = __builtin_bit_cast(bf16x8, p8);                                   \
        }                                                                              \
        setprio1();                                                                    \
        _Pragma("unroll")                                                              \
        for (int qi = 0; qi < QI_; qi++) {                                             \
            o2[qi][0] = __builtin_amdgcn_mfma_f32_16x16x32_bf16(CUR.va0, pk[qi], o2[qi][0], 0, 0, 0); \
            o2[qi][1] = __builtin_amdgcn_mfma_f32_16x16x32_bf16(CUR.va1, pk[qi], o2[qi][1], 0, 0, 0); \
            o2[qi][2] = __builtin_amdgcn_mfma_f32_16x16x32_bf16(CUR.va2, pk[qi], o2[qi][2], 0, 0, 0); \
            o2[qi][3] = __builtin_amdgcn_mfma_f32_16x16x32_bf16(CUR.va3, pk[qi], o2[qi][3], 0, 0, 0); \
            lacc[qi]  = __builtin_amdgcn_mfma_f32_16x16x32_bf16(ones8,   pk[qi], lacc[qi], 0, 0, 0); \
        }                                                                              \
        setprio0();                                                                    \
        /* ---- tail: QK(t_+1) from NXT (overlapped with frag-read latency) ---- */    \
        if (t_ < NT2_ - 1) {                                                           \
            asm volatile("s_waitcnt lgkmcnt(0)" ::: "memory"); /* NXT frags landed */  \
            schedbar0();                              /* rule #18: pin MFMAs below */  \
            setprio1();                                                                \
            _Pragma("unroll")                                                          \
            for (int qi = 0; qi < QI_; qi++) {                                         \
                f32x4 zA = (f32x4){0.f,0.f,0.f,0.f};                                   \
                zA = __builtin_amdgcn_mfma_f32_16x16x32_bf16(NXT.kfA0, qf[qi][0], zA, 0, 0, 0); \
                zA = __builtin_amdgcn_mfma_f32_16x16x32_bf16(NXT.kfA1, qf[qi][1], zA, 0, 0, 0); \
                SNXT.sA[qi] = zA;                                                      \
                f32x4 zB = (f32x4){0.f,0.f,0.f,0.f};                                   \
                zB = __builtin_amdgcn_mfma_f32_16x16x32_bf16(NXT.kfB0, qf[qi][0], zB, 0, 0, 0); \
                zB = __builtin_amdgcn_mfma_f32_16x16x32_bf16(NXT.kfB1, qf[qi][1], zB, 0, 0, 0); \
                SNXT.sB[qi] = zB;                                                      \
            }                                                                          \
            setprio0();                                                                \
        }                                                                              \
    }

    for (int t = 0; t < NT2_; t += 2) {
        ATTN_STEP(t,     fA, fB, sX, sY);
        ATTN_STEP(t + 1, fB, fA, sY, sX);
    }
#undef ATTN_STEP

    __syncthreads();   // all waves done with LDS K/V buffers before overlay

    // ---- epilogue: cross-wave reduction of O^T partials and denominators ----
    float* o_red0 = (float*)smem;            // [48 q][68 c]
    float* o_red1 = o_red0 + QT_*68;
    float* l_red  = o_red1 + QT_*68;         // [4][48]

    if (lane < 16) {
        #pragma unroll
        for (int qi = 0; qi < QI_; qi++) l_red[wave*QT_ + qi*16 + l16] = lacc[qi][0];
    }
    if (wave < 2) {
        float* od = (wave == 0) ? o_red0 : o_red1;
        #pragma unroll
        for (int qi = 0; qi < QI_; qi++)
            #pragma unroll
            for (int ct = 0; ct < 4; ct++)
                *(f32x4*)&od[(qi*16 + l16)*68 + ct*16 + quad*4] = o2[qi][ct];
    }
    __syncthreads();
    if (wave >= 2) {
        float* od = (wave == 2) ? o_red0 : o_red1;
        #pragma unroll
        for (int qi = 0; qi < QI_; qi++)
            #pragma unroll
            for (int ct = 0; ct < 4; ct++) {
                f32x4* p = (f32x4*)&od[(qi*16 + l16)*68 + ct*16 + quad*4];
                *p += o2[qi][ct];
            }
    }
    __syncthreads();
    if (tid < QT_) {
        float s = (l_red[tid] + l_red[QT_ + tid]) + (l_red[2*QT_ + tid] + l_red[3*QT_ + tid]);
        l_red[tid] = 1.f / s;
    }
    __syncthreads();

    float gmm = gamma_p[0];
    int c = tid >> 2, q4 = tid & 3;
    const float* xrow = x + ((size_t)b*C_ + c)*N_ + n_base;
    float* orow = out + ((size_t)b*C_ + c)*N_ + n_base;
    #pragma unroll
    for (int i = 0; i < QI_; i++) {
        int q0 = q4*4 + i*16;
        float4 xv = *(const float4*)(xrow + q0);
        float4 ov;
        float v0 = (o_red0[(q0+0)*68 + c] + o_red1[(q0+0)*68 + c]) * l_red[q0+0];
        float v1 = (o_red0[(q0+1)*68 + c] + o_red1[(q0+1)*68 + c]) * l_red[q0+1];
        float v2 = (o_red0[(q0+2)*68 + c] + o_red1[(q0+2)*68 + c]) * l_red[q0+2];
        float v3 = (o_red0[(q0+3)*68 + c] + o_red1[(q0+3)*68 + c]) * l_red[q0+3];
        ov.x = fmaf(gmm, v0, xv.x);
        ov.y = fmaf(gmm, v1, xv.y);
        ov.z = fmaf(gmm, v2, xv.z);
        ov.w = fmaf(gmm, v3, xv.w);
        *(float4*)(orow + q0) = ov;
    }
}

extern "C" void kernel_launch(void* const* d_in, const int* in_sizes, int n_in,
                              void* d_out, int out_size, void* d_ws, size_t ws_size,
                              hipStream_t stream) {
    const float* c2    = (const float*)d_in[0];
    const float* x     = (const float*)d_in[1];
    const float* w_ea1 = (const float*)d_in[2];
    const float* bn_w  = (const float*)d_in[3];
    const float* bn_b  = (const float*)d_in[4];
    const float* bn_m  = (const float*)d_in[5];
    const float* bn_v  = (const float*)d_in[6];
    const float* w_ea2 = (const float*)d_in[7];
    const float* b_ea2 = (const float*)d_in[8];
    const float* w_q   = (const float*)d_in[9];
    const float* b_q   = (const float*)d_in[10];
    const float* gamma = (const float*)d_in[11];
    float* out = (float*)d_out;

    char* ws = (char*)d_ws;
    unsigned short* kb   = (unsigned short*)(ws + 0);       // 1179648 B
    unsigned short* vb   = (unsigned short*)(ws + 1179648); // 1179648 B

    prep_kernel<<<dim3((B_*M_)/32), dim3(256), 0, stream>>>(x, c2, w_q, b_q,
        w_ea1, bn_w, bn_b, bn_m, bn_v, w_ea2, b_ea2, kb, vb);
    attn_kernel<<<dim3(B_*QB_), dim3(256), 0, stream>>>(w_q, b_q, kb, vb, x, gamma, out);
}

// Round 14
// 139.848 us; speedup vs baseline: 1.0696x; 1.0443x over previous
//
#include <hip/hip_runtime.h>
#include <stdint.h>

#define B_ 4
#define C_ 64
#define H_ 96
#define W_ 96
#define HP_ 48
#define WP_ 48
#define N_ (H_*W_)      // 9216
#define M_ (HP_*WP_)    // 2304
#define KD_ 64
#define OD_ 64
#define BN_EPS 1e-5f
#define LOG2E 1.4426950408889634f
#define QT_ 48                        // q-tile: 768 blocks
#define QI_ (QT_/16)                  // 3 q-frags per block
#define QB_ (N_/QT_)                  // 192 q-tiles per batch
#define KVB_ 128                      // m-tile 128
#define NT2_ (M_/KVB_)                // 18 m-tiles (even — 2x unroll relies on it)
#define KBUF_ 16384                   // K tile bytes: 128 rows x 64 k x 2
#define BUF_ 32768                    // K + V per buffer
// total smem = 2*BUF_ = 65536 -> 2 blocks/CU

typedef __bf16 bf16_t;
typedef bf16_t bf16x8 __attribute__((ext_vector_type(8)));
typedef bf16_t bf16x4 __attribute__((ext_vector_type(4)));
typedef float f32x4 __attribute__((ext_vector_type(4)));
typedef short short4v __attribute__((ext_vector_type(4)));
typedef short short8v __attribute__((ext_vector_type(8)));

static __device__ __forceinline__ unsigned short f2bf(float f) {
    unsigned int u = __builtin_bit_cast(unsigned int, f);
    u += 0x7fffu + ((u >> 16) & 1u);
    return (unsigned short)(u >> 16);
}

// async global->LDS DMA, 16B per lane. LDS dest linear per wave; GLOBAL
// source is per-lane (staged row permutation + chunk swizzle are free).
static __device__ __forceinline__ void gl_lds16(const unsigned short* g, unsigned short* l) {
#if __has_builtin(__builtin_amdgcn_global_load_lds)
    __builtin_amdgcn_global_load_lds(
        (const __attribute__((address_space(1))) unsigned int*)(const void*)g,
        (__attribute__((address_space(3))) unsigned int*)(void*)l, 16, 0, 0);
#endif
}

static __device__ __forceinline__ void setprio1() {
#if __has_builtin(__builtin_amdgcn_s_setprio)
    __builtin_amdgcn_s_setprio(1);
#endif
}
static __device__ __forceinline__ void setprio0() {
#if __has_builtin(__builtin_amdgcn_s_setprio)
    __builtin_amdgcn_s_setprio(0);
#endif
}
static __device__ __forceinline__ void schedbar0() {
#if __has_builtin(__builtin_amdgcn_sched_barrier)
    __builtin_amdgcn_sched_barrier(0);
#endif
}
static __device__ __forceinline__ void rawbar() {
#if __has_builtin(__builtin_amdgcn_s_barrier)
    __builtin_amdgcn_s_barrier();
#else
    __syncthreads();
#endif
}

// ---------------- Kernel 1: fused pool + edge attention + SCALED key conv ----------
// R14: prep rebuilt for the LDS pipe + tail. (1) grid 288->144, block 512,
// m-tile 64 -> single scheduling round (was 2). (2) wave-uniform channel
// groups (wave w = readfirstlane(tid>>6) owns k-channels w*8..+7, lane = m)
// so weight reads are SGPR s_load (SMEM/K$ path) — deletes ALL broadcast
// ds_read_b128 weight reads and the 48KB LDS weight staging. Accumulation
// order unchanged -> kb/vb bit-identical to R13.
__global__ __launch_bounds__(512) void prep_kernel(
    const float* __restrict__ x, const float* __restrict__ c2,
    const float* __restrict__ wq, const float* __restrict__ bq,
    const float* __restrict__ w1, const float* __restrict__ bnw, const float* __restrict__ bnb,
    const float* __restrict__ bnm, const float* __restrict__ bnv,
    const float* __restrict__ w2, const float* __restrict__ b2,
    unsigned short* __restrict__ kb, unsigned short* __restrict__ vb) {

    __shared__ float xs[C_*65];     // [64 c][64 m +1 pad]
    __shared__ float c2s[C_*65];
    __shared__ float red[8][64];
    __shared__ float eaf[64];

    int tid = threadIdx.x;
    int b = blockIdx.x / 36;                   // 36 blocks per batch
    int m0 = (blockIdx.x % 36) * 64;

    // ---- pooling (coalesced-ish 2x2 max), vb write ----
    for (int j = tid; j < 4096; j += 512) {
        int c = j >> 6, p = j & 63;
        int m = m0 + p;
        int hp = m / WP_, wp = m % WP_;
        size_t base = ((size_t)(b*C_ + c)*H_ + 2*hp)*W_ + 2*wp;
        const float* px = x + base;
        float mx = fmaxf(fmaxf(px[0], px[1]), fmaxf(px[W_], px[W_+1]));
        xs[c*65 + p] = mx;
        vb[(size_t)(b*C_ + c)*M_ + m] = f2bf(mx);
        const float* pc = c2 + base;
        c2s[c*65 + p] = fmaxf(fmaxf(pc[0], pc[1]), fmaxf(pc[W_], pc[W_+1]));
    }
    __syncthreads();

    int ml = tid & 63;
    int wv_ = __builtin_amdgcn_readfirstlane(tid >> 6);   // 0..7, wave-uniform SGPR
    int m = m0 + ml;

    // ---- edge attention first (weights via scalar loads, wave-uniform rows) ----
    float g[8] = {0,0,0,0,0,0,0,0};
    for (int c = 0; c < 2*C_; c += 4) {
        const float* srcb = (c < C_) ? &c2s[c*65] : &xs[(c - C_)*65];
        float x0 = srcb[ml], x1 = srcb[65+ml], x2 = srcb[130+ml], x3 = srcb[195+ml];
        #pragma unroll
        for (int oi = 0; oi < 8; oi++) {
            const float4 wvv = *(const float4*)&w1[(size_t)(wv_*8 + oi)*(2*C_) + c];
            g[oi] = fmaf(wvv.x, x0, fmaf(wvv.y, x1, fmaf(wvv.z, x2, fmaf(wvv.w, x3, g[oi]))));
        }
    }
    float z = 0.f;
    #pragma unroll
    for (int oi = 0; oi < 8; oi++) {
        int o = wv_*8 + oi;
        float sc = bnw[o] * rsqrtf(bnv[o] + BN_EPS);
        float t = (g[oi] - bnm[o]) * sc + bnb[o];
        z += w2[o] * fmaxf(t, 0.f);
    }
    red[wv_][ml] = z;
    __syncthreads();
    if (wv_ == 0) {
        float s = b2[0];
        #pragma unroll
        for (int i = 0; i < 8; i++) s += red[i][ml];
        eaf[ml] = LOG2E / (1.f + __builtin_amdgcn_exp2f(-s * LOG2E));
    }
    __syncthreads();

    // ---- key conv, scaled by eaf[m] (weights via scalar loads) ----
    float h[8] = {0,0,0,0,0,0,0,0};
    for (int c = 0; c < C_; c += 4) {
        float x0 = xs[c*65+ml], x1 = xs[(c+1)*65+ml], x2 = xs[(c+2)*65+ml], x3 = xs[(c+3)*65+ml];
        #pragma unroll
        for (int oi = 0; oi < 8; oi++) {
            const float4 wvv = *(const float4*)&wq[(size_t)(wv_*8 + oi)*C_ + c];
            h[oi] = fmaf(wvv.x, x0, fmaf(wvv.y, x1, fmaf(wvv.z, x2, fmaf(wvv.w, x3, h[oi]))));
        }
    }
    float fac = eaf[ml];
    unsigned short tmp[8];
    #pragma unroll
    for (int oi = 0; oi < 8; oi++) tmp[oi] = f2bf((h[oi] + bq[wv_*8 + oi]) * fac);
    *(uint4*)&kb[((size_t)b*M_ + m)*KD_ + wv_*8] = *(const uint4*)tmp;
}

// ---------------- Kernel 2: flash attention (R13, unchanged) ----------------
// 128-m tiles, K=32 PV via staged row permutation, T15 QK-hoist, no-ea
// (folded into kb), P = exp2(st) directly.
__global__ __launch_bounds__(256, 2) void attn_kernel(
    const float* __restrict__ wq, const float* __restrict__ bq,
    const unsigned short* __restrict__ kb, const unsigned short* __restrict__ vb,
    const float* __restrict__ x, const float* __restrict__ gamma_p, float* __restrict__ out) {

    // [K 16384 | V 16384] x2 = 65536 B
    // prologue overlay: qlds 6144 @0 (consumed before STAGE(0) overwrites)
    // epilogue overlay: o_red 26112 + l_red 768 = 26880 B @0 (fits)
    __shared__ __align__(16) char smem[65536];

    int tid = threadIdx.x;
    int wave = tid >> 6, lane = tid & 63, quad = lane >> 4, l16 = lane & 15;
    int blk = blockIdx.x;
    int b = (blk & 7) >> 1;                       // batch pinned to XCD pair
    int n_base = ((blk & 1) * (QB_/2) + (blk >> 3)) * QT_;
    int xsw = l16 & 7;

    // ---- fused q-conv via compensated bf16 MFMA (R10, unchanged) ----
    unsigned short* qlds = (unsigned short*)smem; // [48 n][64 k] bf16 swz (buf0 overlay)
    {
        const float* xb = x + (size_t)b*C_*N_ + n_base;
        bf16x8 wh0, wh1, wl0, wl1;
        {
            float w8[8];
            unsigned short hs[8], ls[8];
            const float* wp0 = wq + (size_t)(wave*16 + l16)*C_ + quad*8;
            *(float4*)&w8[0] = *(const float4*)wp0;
            *(float4*)&w8[4] = *(const float4*)(wp0 + 4);
            #pragma unroll
            for (int j = 0; j < 8; j++) {
                hs[j] = f2bf(w8[j]);
                float hf = __builtin_bit_cast(float, (unsigned int)hs[j] << 16);
                ls[j] = f2bf(w8[j] - hf);
            }
            wh0 = __builtin_bit_cast(bf16x8, *(const uint4*)hs);
            wl0 = __builtin_bit_cast(bf16x8, *(const uint4*)ls);
            const float* wp1 = wp0 + 32;
            *(float4*)&w8[0] = *(const float4*)wp1;
            *(float4*)&w8[4] = *(const float4*)(wp1 + 4);
            #pragma unroll
            for (int j = 0; j < 8; j++) {
                hs[j] = f2bf(w8[j]);
                float hf = __builtin_bit_cast(float, (unsigned int)hs[j] << 16);
                ls[j] = f2bf(w8[j] - hf);
            }
            wh1 = __builtin_bit_cast(bf16x8, *(const uint4*)hs);
            wl1 = __builtin_bit_cast(bf16x8, *(const uint4*)ls);
        }
        float4 bq4 = *(const float4*)(bq + wave*16 + quad*4);

        f32x4 qacc[3];
        #pragma unroll
        for (int t = 0; t < 3; t++) qacc[t] = (f32x4){0.f,0.f,0.f,0.f};

        #pragma unroll
        for (int t = 0; t < 3; t++) {
            #pragma unroll
            for (int h = 0; h < 2; h++) {
                float v8[8];
                #pragma unroll
                for (int j = 0; j < 8; j++)
                    v8[j] = xb[(size_t)(h*32 + quad*8 + j)*N_ + t*16 + l16];
                unsigned short hs[8], ls[8];
                #pragma unroll
                for (int j = 0; j < 8; j++) {
                    hs[j] = f2bf(v8[j]);
                    float hf = __builtin_bit_cast(float, (unsigned int)hs[j] << 16);
                    ls[j] = f2bf(v8[j] - hf);
                }
                bf16x8 xh = __builtin_bit_cast(bf16x8, *(const uint4*)hs);
                bf16x8 xl = __builtin_bit_cast(bf16x8, *(const uint4*)ls);
                bf16x8 wh = h ? wh1 : wh0;
                bf16x8 wl = h ? wl1 : wl0;
#if __has_builtin(__builtin_amdgcn_mfma_f32_16x16x32_bf16)
                qacc[t] = __builtin_amdgcn_mfma_f32_16x16x32_bf16(wh, xh, qacc[t], 0, 0, 0);
                qacc[t] = __builtin_amdgcn_mfma_f32_16x16x32_bf16(wl, xh, qacc[t], 0, 0, 0);
                qacc[t] = __builtin_amdgcn_mfma_f32_16x16x32_bf16(wh, xl, qacc[t], 0, 0, 0);
#endif
            }
        }
        #pragma unroll
        for (int t = 0; t < 3; t++) {
            unsigned short q4[4];
            q4[0] = f2bf(qacc[t][0] + bq4.x);
            q4[1] = f2bf(qacc[t][1] + bq4.y);
            q4[2] = f2bf(qacc[t][2] + bq4.z);
            q4[3] = f2bf(qacc[t][3] + bq4.w);
            int n_abs = t*16 + l16;
            int kc = wave*2 + (quad >> 1);
            *(uint2*)&qlds[n_abs*64 + ((kc ^ (n_abs & 7)) << 3) + (quad & 1)*4] =
                *(const uint2*)q4;
        }
    }
    asm volatile("s_waitcnt lgkmcnt(0)" ::: "memory"); // qlds writes done (own wave)
    __syncthreads();                                   // all waves' q written

    // Q B-frags: B[col=q=qi*16+l16][k=quad*8+j]
    bf16x8 qf[QI_][2];
    #pragma unroll
    for (int qi = 0; qi < QI_; qi++) {
        const unsigned short* qp = qlds + (qi*16 + l16)*64;
        qf[qi][0] = __builtin_bit_cast(bf16x8, *(const uint4*)(qp + ((quad     ^ xsw) << 3)));
        qf[qi][1] = __builtin_bit_cast(bf16x8, *(const uint4*)(qp + (((quad+4) ^ xsw) << 3)));
    }
    asm volatile("s_waitcnt lgkmcnt(0)" ::: "memory"); // qf reads landed (own wave)
    __syncthreads();          // all waves done reading qlds before STAGE overwrites

    f32x4 o2[QI_][4]; // O^T partial: [qi][ct]
    f32x4 lacc[QI_];  // denominator partials via ones-MFMA
    #pragma unroll
    for (int qi = 0; qi < QI_; qi++) {
        lacc[qi] = (f32x4){0.f,0.f,0.f,0.f};
        #pragma unroll
        for (int ct = 0; ct < 4; ct++) o2[qi][ct] = (f32x4){0.f,0.f,0.f,0.f};
    }
    const unsigned short ones_u[8] = {0x3F80,0x3F80,0x3F80,0x3F80,0x3F80,0x3F80,0x3F80,0x3F80};
    bf16x8 ones8 = __builtin_bit_cast(bf16x8, *(const uint4*)ones_u);

    const unsigned short* kbB = kb + (size_t)b*M_*KD_;
    const unsigned short* vbB = vb + (size_t)b*C_*M_;

    // ---- staging invariants ----
    // K: LDS row R = p*32 + r8 holds global m = mb + p*32 + mloc(r8);
    //    mloc = (ii>>2)*8 + half*4 + (ii&3) — the P-repack-free permutation.
    int r8  = tid >> 3;                       // 0..31
    int mloc = (((r8 & 15) >> 2) << 3) + ((r8 >> 4) << 2) + (r8 & 3);
    int kcs = ((tid & 7) ^ (r8 & 7)) << 3;    // K chunk swizzle (shorts)
    int c16 = tid >> 4;                       // 0..15 (V c-row within pass)
    int vcs = ((tid & 15) ^ (c16 & 7)) << 3;  // V chunk swizzle (shorts)

    auto STAGE = [&](int mb, char* buf) {
        unsigned short* kd = (unsigned short*)buf;
        unsigned short* vd = (unsigned short*)(buf + KBUF_);
        gl_lds16(kbB + (size_t)(mb +  0 + mloc)*KD_ + kcs, kd + 0*2048 + tid*8);
        gl_lds16(kbB + (size_t)(mb + 32 + mloc)*KD_ + kcs, kd + 1*2048 + tid*8);
        gl_lds16(kbB + (size_t)(mb + 64 + mloc)*KD_ + kcs, kd + 2*2048 + tid*8);
        gl_lds16(kbB + (size_t)(mb + 96 + mloc)*KD_ + kcs, kd + 3*2048 + tid*8);
        gl_lds16(vbB + (size_t)( 0 + c16)*M_ + mb + vcs, vd + 0*2048 + tid*8);
        gl_lds16(vbB + (size_t)(16 + c16)*M_ + mb + vcs, vd + 1*2048 + tid*8);
        gl_lds16(vbB + (size_t)(32 + c16)*M_ + mb + vcs, vd + 2*2048 + tid*8);
        gl_lds16(vbB + (size_t)(48 + c16)*M_ + mb + vcs, vd + 3*2048 + tid*8);
    };

    STAGE(0,    smem);
    STAGE(128,  smem + BUF_);
    asm volatile("s_waitcnt vmcnt(8)" ::: "memory");   // tile0's 8 DMA done (own wave)
    rawbar();                                          // => all waves' tile0 done
    asm volatile("" ::: "memory");

    // read offsets (shorts)
    int kOffA0 = (wave*32 + l16)*64 + ((quad       ^ xsw) << 3);
    int kOffA1 = (wave*32 + l16)*64 + (((quad + 4) ^ xsw) << 3);
    int kOffB0 = kOffA0 + 16*64;
    int kOffB1 = kOffA1 + 16*64;
    int vch    = ((wave*4 + quad) ^ xsw) << 3;

    // frag + st double-buffers: NAMED sets (constant/unroll-idx access only)
    struct FragSet {
        bf16x8 kfA0, kfA1, kfB0, kfB1;
        bf16x8 va0, va1, va2, va3;
    };
    struct StSet { f32x4 sA[QI_]; f32x4 sB[QI_]; };
    FragSet fA, fB;
    StSet sX, sY;

    // read frag set for tile 0 into fA (from buf0), then QK(0) -> sX
    {
        unsigned short* kc = (unsigned short*)smem;
        unsigned short* vc = (unsigned short*)(smem + KBUF_);
        fA.kfA0 = __builtin_bit_cast(bf16x8, *(const uint4*)(kc + kOffA0));
        fA.kfA1 = __builtin_bit_cast(bf16x8, *(const uint4*)(kc + kOffA1));
        fA.kfB0 = __builtin_bit_cast(bf16x8, *(const uint4*)(kc + kOffB0));
        fA.kfB1 = __builtin_bit_cast(bf16x8, *(const uint4*)(kc + kOffB1));
        fA.va0 = __builtin_bit_cast(bf16x8, *(const uint4*)(vc + (0*16 + l16)*KVB_ + vch));
        fA.va1 = __builtin_bit_cast(bf16x8, *(const uint4*)(vc + (1*16 + l16)*KVB_ + vch));
        fA.va2 = __builtin_bit_cast(bf16x8, *(const uint4*)(vc + (2*16 + l16)*KVB_ + vch));
        fA.va3 = __builtin_bit_cast(bf16x8, *(const uint4*)(vc + (3*16 + l16)*KVB_ + vch));
    }
    asm volatile("s_waitcnt lgkmcnt(0)" ::: "memory");
    schedbar0();
    #pragma unroll
    for (int qi = 0; qi < QI_; qi++) {
        f32x4 zA = (f32x4){0.f,0.f,0.f,0.f};
        zA = __builtin_amdgcn_mfma_f32_16x16x32_bf16(fA.kfA0, qf[qi][0], zA, 0, 0, 0);
        zA = __builtin_amdgcn_mfma_f32_16x16x32_bf16(fA.kfA1, qf[qi][1], zA, 0, 0, 0);
        sX.sA[qi] = zA;
        f32x4 zB = (f32x4){0.f,0.f,0.f,0.f};
        zB = __builtin_amdgcn_mfma_f32_16x16x32_bf16(fA.kfB0, qf[qi][0], zB, 0, 0, 0);
        zB = __builtin_amdgcn_mfma_f32_16x16x32_bf16(fA.kfB1, qf[qi][1], zB, 0, 0, 0);
        sX.sB[qi] = zB;
    }

// one pipeline step: exp+PV of tile T_ (SCUR/CUR), prefetch T_+1 frags into
// NXT, then QK(T_+1) -> SNXT at the tail. P = exp2(st) directly (no shift).
#define ATTN_STEP(T_, CUR, NXT, SCUR, SNXT)                                            \
    {                                                                                  \
        const int t_ = (T_);                                                           \
        if (t_ < NT2_ - 1) {                                                           \
            asm volatile("s_waitcnt vmcnt(0)" ::: "memory");  /* tile t_+1 DMA done */ \
            schedbar0();                                                               \
            rawbar();                   /* acquire buf[(t_+1)&1], release buf[t_&1] */ \
            asm volatile("" ::: "memory");                                             \
            schedbar0();                                                               \
            if (t_ + 2 < NT2_) { STAGE((t_ + 2)*KVB_, smem + (t_ & 1)*BUF_); }         \
            unsigned short* kc_ = (unsigned short*)(smem + ((t_ + 1) & 1)*BUF_);       \
            unsigned short* vc_ = (unsigned short*)(smem + ((t_ + 1) & 1)*BUF_ + KBUF_); \
            NXT.kfA0 = __builtin_bit_cast(bf16x8, *(const uint4*)(kc_ + kOffA0));      \
            NXT.kfA1 = __builtin_bit_cast(bf16x8, *(const uint4*)(kc_ + kOffA1));      \
            NXT.kfB0 = __builtin_bit_cast(bf16x8, *(const uint4*)(kc_ + kOffB0));      \
            NXT.kfB1 = __builtin_bit_cast(bf16x8, *(const uint4*)(kc_ + kOffB1));      \
            NXT.va0 = __builtin_bit_cast(bf16x8, *(const uint4*)(vc_ + (0*16 + l16)*KVB_ + vch)); \
            NXT.va1 = __builtin_bit_cast(bf16x8, *(const uint4*)(vc_ + (1*16 + l16)*KVB_ + vch)); \
            NXT.va2 = __builtin_bit_cast(bf16x8, *(const uint4*)(vc_ + (2*16 + l16)*KVB_ + vch)); \
            NXT.va3 = __builtin_bit_cast(bf16x8, *(const uint4*)(vc_ + (3*16 + l16)*KVB_ + vch)); \
            schedbar0();                                                               \
        }                                                                              \
        /* ---- exp(t_) + PV(t_): the only serial chain this step ---- */              \
        bf16x8 pk[QI_];                                                                \
        _Pragma("unroll")                                                              \
        for (int qi = 0; qi < QI_; qi++) {                                             \
            f32x4 pA, pB;                                                              \
            pA[0] = __builtin_amdgcn_exp2f(SCUR.sA[qi][0]);                            \
            pA[1] = __builtin_amdgcn_exp2f(SCUR.sA[qi][1]);                            \
            pA[2] = __builtin_amdgcn_exp2f(SCUR.sA[qi][2]);                            \
            pA[3] = __builtin_amdgcn_exp2f(SCUR.sA[qi][3]);                            \
            pB[0] = __builtin_amdgcn_exp2f(SCUR.sB[qi][0]);                            \
            pB[1] = __builtin_amdgcn_exp2f(SCUR.sB[qi][1]);                            \
            pB[2] = __builtin_amdgcn_exp2f(SCUR.sB[qi][2]);                            \
            pB[3] = __builtin_amdgcn_exp2f(SCUR.sB[qi][3]);                            \
            short4v pa = __builtin_bit_cast(short4v, __builtin_convertvector(pA, bf16x4)); \
            short4v pb = __builtin_bit_cast(short4v, __builtin_convertvector(pB, bf16x4)); \
            short8v p8 = __builtin_shufflevector(pa, pb, 0, 1, 2, 3, 4, 5, 6, 7);      \
            pk[qi] = __builtin_bit_cast(bf16x8, p8);                                   \
        }                                                                              \
        setprio1();                                                                    \
        _Pragma("unroll")                                                              \
        for (int qi = 0; qi < QI_; qi++) {                                             \
            o2[qi][0] = __builtin_amdgcn_mfma_f32_16x16x32_bf16(CUR.va0, pk[qi], o2[qi][0], 0, 0, 0); \
            o2[qi][1] = __builtin_amdgcn_mfma_f32_16x16x32_bf16(CUR.va1, pk[qi], o2[qi][1], 0, 0, 0); \
            o2[qi][2] = __builtin_amdgcn_mfma_f32_16x16x32_bf16(CUR.va2, pk[qi], o2[qi][2], 0, 0, 0); \
            o2[qi][3] = __builtin_amdgcn_mfma_f32_16x16x32_bf16(CUR.va3, pk[qi], o2[qi][3], 0, 0, 0); \
            lacc[qi]  = __builtin_amdgcn_mfma_f32_16x16x32_bf16(ones8,   pk[qi], lacc[qi], 0, 0, 0); \
        }                                                                              \
        setprio0();                                                                    \
        /* ---- tail: QK(t_+1) from NXT (overlapped with frag-read latency) ---- */    \
        if (t_ < NT2_ - 1) {                                                           \
            asm volatile("s_waitcnt lgkmcnt(0)" ::: "memory"); /* NXT frags landed */  \
            schedbar0();                              /* rule #18: pin MFMAs below */  \
            setprio1();                                                                \
            _Pragma("unroll")                                                          \
            for (int qi = 0; qi < QI_; qi++) {                                         \
                f32x4 zA = (f32x4){0.f,0.f,0.f,0.f};                                   \
                zA = __builtin_amdgcn_mfma_f32_16x16x32_bf16(NXT.kfA0, qf[qi][0], zA, 0, 0, 0); \
                zA = __builtin_amdgcn_mfma_f32_16x16x32_bf16(NXT.kfA1, qf[qi][1], zA, 0, 0, 0); \
                SNXT.sA[qi] = zA;                                                      \
                f32x4 zB = (f32x4){0.f,0.f,0.f,0.f};                                   \
                zB = __builtin_amdgcn_mfma_f32_16x16x32_bf16(NXT.kfB0, qf[qi][0], zB, 0, 0, 0); \
                zB = __builtin_amdgcn_mfma_f32_16x16x32_bf16(NXT.kfB1, qf[qi][1], zB, 0, 0, 0); \
                SNXT.sB[qi] = zB;                                                      \
            }                                                                          \
            setprio0();                                                                \
        }                                                                              \
    }

    for (int t = 0; t < NT2_; t += 2) {
        ATTN_STEP(t,     fA, fB, sX, sY);
        ATTN_STEP(t + 1, fB, fA, sY, sX);
    }
#undef ATTN_STEP

    __syncthreads();   // all waves done with LDS K/V buffers before overlay

    // ---- epilogue: cross-wave reduction of O^T partials and denominators ----
    float* o_red0 = (float*)smem;            // [48 q][68 c]
    float* o_red1 = o_red0 + QT_*68;
    float* l_red  = o_red1 + QT_*68;         // [4][48]

    if (lane < 16) {
        #pragma unroll
        for (int qi = 0; qi < QI_; qi++) l_red[wave*QT_ + qi*16 + l16] = lacc[qi][0];
    }
    if (wave < 2) {
        float* od = (wave == 0) ? o_red0 : o_red1;
        #pragma unroll
        for (int qi = 0; qi < QI_; qi++)
            #pragma unroll
            for (int ct = 0; ct < 4; ct++)
                *(f32x4*)&od[(qi*16 + l16)*68 + ct*16 + quad*4] = o2[qi][ct];
    }
    __syncthreads();
    if (wave >= 2) {
        float* od = (wave == 2) ? o_red0 : o_red1;
        #pragma unroll
        for (int qi = 0; qi < QI_; qi++)
            #pragma unroll
            for (int ct = 0; ct < 4; ct++) {
                f32x4* p = (f32x4*)&od[(qi*16 + l16)*68 + ct*16 + quad*4];
                *p += o2[qi][ct];
            }
    }
    __syncthreads();
    if (tid < QT_) {
        float s = (l_red[tid] + l_red[QT_ + tid]) + (l_red[2*QT_ + tid] + l_red[3*QT_ + tid]);
        l_red[tid] = 1.f / s;
    }
    __syncthreads();

    float gmm = gamma_p[0];
    int c = tid >> 2, q4 = tid & 3;
    const float* xrow = x + ((size_t)b*C_ + c)*N_ + n_base;
    float* orow = out + ((size_t)b*C_ + c)*N_ + n_base;
    #pragma unroll
    for (int i = 0; i < QI_; i++) {
        int q0 = q4*4 + i*16;
        float4 xv = *(const float4*)(xrow + q0);
        float4 ov;
        float v0 = (o_red0[(q0+0)*68 + c] + o_red1[(q0+0)*68 + c]) * l_red[q0+0];
        float v1 = (o_red0[(q0+1)*68 + c] + o_red1[(q0+1)*68 + c]) * l_red[q0+1];
        float v2 = (o_red0[(q0+2)*68 + c] + o_red1[(q0+2)*68 + c]) * l_red[q0+2];
        float v3 = (o_red0[(q0+3)*68 + c] + o_red1[(q0+3)*68 + c]) * l_red[q0+3];
        ov.x = fmaf(gmm, v0, xv.x);
        ov.y = fmaf(gmm, v1, xv.y);
        ov.z = fmaf(gmm, v2, xv.z);
        ov.w = fmaf(gmm, v3, xv.w);
        *(float4*)(orow + q0) = ov;
    }
}

extern "C" void kernel_launch(void* const* d_in, const int* in_sizes, int n_in,
                              void* d_out, int out_size, void* d_ws, size_t ws_size,
                              hipStream_t stream) {
    const float* c2    = (const float*)d_in[0];
    const float* x     = (const float*)d_in[1];
    const float* w_ea1 = (const float*)d_in[2];
    const float* bn_w  = (const float*)d_in[3];
    const float* bn_b  = (const float*)d_in[4];
    const float* bn_m  = (const float*)d_in[5];
    const float* bn_v  = (const float*)d_in[6];
    const float* w_ea2 = (const float*)d_in[7];
    const float* b_ea2 = (const float*)d_in[8];
    const float* w_q   = (const float*)d_in[9];
    const float* b_q   = (const float*)d_in[10];
    const float* gamma = (const float*)d_in[11];
    float* out = (float*)d_out;

    char* ws = (char*)d_ws;
    unsigned short* kb   = (unsigned short*)(ws + 0);       // 1179648 B
    unsigned short* vb   = (unsigned short*)(ws + 1179648); // 1179648 B

    prep_kernel<<<dim3(B_*36), dim3(512), 0, stream>>>(x, c2, w_q, b_q,
        w_ea1, bn_w, bn_b, bn_m, bn_v, w_ea2, b_ea2, kb, vb);
    attn_kernel<<<dim3(B_*QB_), dim3(256), 0, stream>>>(w_q, b_q, kb, vb, x, gamma, out);
}